// Round 9
// baseline (1835.200 us; speedup 1.0000x reference)
//
#include <hip/hip_runtime.h>

#define NB    1024
#define TSEQ  336
#define DIM   64
#define GATES 256
#define PRED  96

// ========================= MULTI-KERNEL PIPELINE (v2) ========================
// R8 proved the decomposition (1427 us). R9 change: lstm_recur combines gates
// IN-REGISTER via shfl_xor (lane = (row,j,gate), 4-lane gate groups) with a
// double-buffered Hs -> ONE barrier/step, no LDS partials round trip.
// gemm_pre stores pre permuted to (j*4+gate) so recur's per-lane pre read is
// perfectly coalesced (pre is consumed only by recur). Dec + fallback verbatim
// from R8 (proven).

__device__ __forceinline__ float sigm(float v)  { return 1.0f / (1.0f + __expf(-v)); }
__device__ __forceinline__ float tanh_(float v) { return 1.0f - 2.0f / (__expf(2.0f * v) + 1.0f); }

__device__ __forceinline__ void fma4v(float& acc, const float4 xv, const float4 w) {
    acc = fmaf(xv.x, w.x, acc); acc = fmaf(xv.y, w.y, acc);
    acc = fmaf(xv.z, w.z, acc); acc = fmaf(xv.w, w.w, acc);
}

// ---------------- kernel 1: pre = in @ W^T + ba + bb (PERMUTED store) -------
// grid: 1024 blocks (one batch row). 512 thr: lane = (gate-row g, k-half kh).
// Store index perm(g) = (g&63)*4 + (g>>6) = j*4+gate for recur coalescing.
extern "C" __global__ void __launch_bounds__(512, 4)
gemm_pre(const float* __restrict__ in,   // [1024][TSEQ][64], pre-offset by t0*64
         const float* __restrict__ W,    // [256][64]
         const float* __restrict__ ba, const float* __restrict__ bb,
         float* __restrict__ pre,        // [1024][tcount][256] (permuted inner)
         int tcount)
{
    __shared__ __align__(16) float xt[2][512];
    __shared__ __align__(16) float pp[2 * 2048];   // [kh][t8*256+g]
    const int tid = threadIdx.x;
    const int row = blockIdx.x;
    const int g   = tid & 255;
    const int kh  = tid >> 8;
    const int gperm = (g & 63) * 4 + (g >> 6);     // j*4 + gate

    float4 w[8];
#pragma unroll
    for (int k4 = 0; k4 < 8; ++k4)
        w[k4] = *reinterpret_cast<const float4*>(W + g * DIM + kh * 32 + k4 * 4);
    const float bs = ba[g] + bb[g];

    const float* rin  = in  + (size_t)row * (TSEQ * DIM);
    float*       rout = pre + (size_t)row * tcount * GATES;
    const int ntile = tcount >> 3;

    xt[0][tid] = rin[tid];
    __syncthreads();
    for (int tile = 0; tile < ntile; ++tile) {
        const int cur = tile & 1;
        float pa[8];
#pragma unroll
        for (int t8 = 0; t8 < 8; ++t8) {
            const float* xb = &xt[cur][t8 * 64 + kh * 32];
            float a = 0.f;
#pragma unroll
            for (int k4 = 0; k4 < 8; ++k4)
                fma4v(a, *reinterpret_cast<const float4*>(xb + k4 * 4), w[k4]);
            pa[t8] = a;
        }
#pragma unroll
        for (int t8 = 0; t8 < 8; ++t8)
            pp[kh * 2048 + t8 * 256 + g] = pa[t8];
        if (tile + 1 < ntile)                       // prefetch next x tile
            xt[cur ^ 1][tid] = rin[(tile + 1) * 512 + tid];
        __syncthreads();
        const int tb = tile * 8;
#pragma unroll
        for (int q = 0; q < 4; ++q) {               // combine kh pairs + store
            const int t8 = q * 2 + kh;
            rout[(size_t)(tb + t8) * GATES + gperm] =
                pp[t8 * 256 + g] + pp[2048 + t8 * 256 + g] + bs;
        }
        __syncthreads();
    }
}

// ---------------- kernel 2: hh-only LSTM recurrence (shfl combine) ----------
// grid: 512 blocks (2 rows each). 512 thr: lane = row*256 + j*4 + gate.
// Weight row = gate*64+j, full K (64 VGPR). One barrier/step via Hs dbuf.
extern "C" __global__ void __launch_bounds__(512, 4)
lstm_recur(const float* __restrict__ pre, int tcount, int t0,
           const float* __restrict__ Whh,
           float* __restrict__ hseq,               // [1024][TSEQ][64] or null
           float* __restrict__ hstate, float* __restrict__ cstate, // [1024][64]
           int zero_init)
{
    __shared__ __align__(16) float Hs[2][128];     // [buf][row*64 + k]
    const int tid  = threadIdx.x;
    const int r0   = blockIdx.x * 2;
    const int row  = tid >> 8;          // 0..1
    const int lidx = tid & 255;         // j*4 + gate
    const int j    = lidx >> 2;
    const int gate = lidx & 3;
    const int grow = gate * 64 + j;     // weight row

    float4 w[16];
#pragma unroll
    for (int k4 = 0; k4 < 16; ++k4)
        w[k4] = *reinterpret_cast<const float4*>(Whh + grow * DIM + k4 * 4);

    float c;
    if (zero_init) {
        c = 0.f;
        if (gate == 0) Hs[0][row * 64 + j] = 0.f;
    } else {
        c = cstate[(r0 + row) * DIM + j];
        if (gate == 0) Hs[0][row * 64 + j] = hstate[(r0 + row) * DIM + j];
    }
    const float* prow = pre + (size_t)(r0 + row) * tcount * GATES + lidx;
    float pvA = prow[0];
    float pvB = prow[GATES];
    __syncthreads();

    int cur = 0;
    float h = 0.f;
    for (int t = 0; t < tcount; ++t) {
        // pre-activation for this lane's gate (pre already includes biases)
        float xa = pvA, xb = 0.f;
        pvA = pvB;
        if (t + 2 < tcount) pvB = prow[(size_t)(t + 2) * GATES];
        const float* hb = Hs[cur] + row * 64;
#pragma unroll
        for (int k4 = 0; k4 < 16; k4 += 2) {        // 2 chains: halve dep latency
            fma4v(xa, *reinterpret_cast<const float4*>(hb + k4 * 4),       w[k4]);
            fma4v(xb, *reinterpret_cast<const float4*>(hb + (k4 + 1) * 4), w[k4 + 1]);
        }
        const float x = xa + xb;
        // gather the 4 gate pre-activations within the aligned 4-lane group
        const float v1 = __shfl_xor(x, 1, 64);
        const float v2 = __shfl_xor(x, 2, 64);
        const float v3 = __shfl_xor(v1, 2, 64);
        // value of gate k lives in {x,v1,v2,v3}[gate ^ k]
        const float vi = (gate == 0) ? x : (gate == 1) ? v1 : (gate == 2) ? v2 : v3;
        const int mf = gate ^ 1;
        const float vf = (mf == 0) ? x : (mf == 1) ? v1 : (mf == 2) ? v2 : v3;
        const int mg = gate ^ 2;
        const float vg = (mg == 0) ? x : (mg == 1) ? v1 : (mg == 2) ? v2 : v3;
        const int mo = gate ^ 3;
        const float vo = (mo == 0) ? x : (mo == 1) ? v1 : (mo == 2) ? v2 : v3;

        const float ig = sigm(vi), fg = sigm(vf), gg = tanh_(vg), og = sigm(vo);
        c = fmaf(fg, c, ig * gg);
        h = og * tanh_(c);
        if (gate == 0) {
            Hs[cur ^ 1][row * 64 + j] = h;          // write NEXT buffer: no race
            if (hseq) hseq[(size_t)(r0 + row) * (TSEQ * DIM) + (size_t)(t0 + t) * DIM + j] = h;
        }
        __syncthreads();                            // ONE barrier per step
        cur ^= 1;
    }
    if (gate == 0) {
        hstate[(r0 + row) * DIM + j] = h;
        cstate[(r0 + row) * DIM + j] = c;
    }
}

// ---------------- kernel 3: decoder (96 zero-state steps) — R8 verbatim -----
#define DWFC 0
#define DP0  4096
#define DP1  4608
#define DH0  5120
#define DH1  5248
#define DDB  5376
#define DBS0 5504
#define DBS1 5760
#define DBFC 6016
#define DSMF 6080

extern "C" __global__ void __launch_bounds__(512, 2)
lstm_dec(const float* __restrict__ Wih0, const float* __restrict__ Wih1,
         const float* __restrict__ Wfc,
         const float* __restrict__ bih0, const float* __restrict__ bhh0,
         const float* __restrict__ bih1, const float* __restrict__ bhh1,
         const float* __restrict__ bfc,
         const float* __restrict__ h1last, float* __restrict__ out)
{
    __shared__ __align__(16) float sm[DSMF];
    const int tid = threadIdx.x;
    const int r0  = blockIdx.x * 2;
    const int rr  = (tid >> 6) & 1;
    const int jj  = tid & 63;
    const int dsub = tid >> 8;          // 0: Wih0 team, 1: Wih1 team
    const int g0d  = tid & 255;

    if (tid < 256) {
        sm[DBS0 + tid] = bih0[tid] + bhh0[tid];
        sm[DBS1 + tid] = bih1[tid] + bhh1[tid];
    }
    if (tid < 64) sm[DBFC + tid] = bfc[tid];
    for (int idx = tid; idx < DIM * DIM; idx += 512) {   // W_fc: (k4,c,j)
        const int j = idx >> 6, k = idx & 63;
        sm[DWFC + (k >> 2) * 256 + (k & 3) * 64 + j] = Wfc[idx];
    }
    if (tid < 128) sm[DDB + tid] = h1last[(r0 + rr) * DIM + jj];

    const float* Wsrc = dsub ? Wih1 : Wih0;
    float4 wd[16];
#pragma unroll
    for (int k4 = 0; k4 < 16; ++k4)
        wd[k4] = *reinterpret_cast<const float4*>(Wsrc + g0d * DIM + k4 * 4);
    __syncthreads();
    const float bfc_j = sm[DBFC + jj];

    for (int p = 0; p < PRED; ++p) {
        if (dsub == 0) {        // cell0: Wih0 . db (2 rows)
            float a0 = 0.f, a1 = 0.f;
#pragma unroll
            for (int k4 = 0; k4 < 16; ++k4) {
                fma4v(a0, *reinterpret_cast<const float4*>(sm + DDB + k4 * 4),      wd[k4]);
                fma4v(a1, *reinterpret_cast<const float4*>(sm + DDB + 64 + k4 * 4), wd[k4]);
            }
            sm[DP0 + g0d] = a0; sm[DP0 + 256 + g0d] = a1;
        }
        __syncthreads();
        if (tid < 128) {        // combine0: c = i*g
            const float* q = sm + DP0 + rr * 256;
            const float pi = sm[DBS0 + jj]        + q[jj];
            const float pg = sm[DBS0 + 128 + jj]  + q[128 + jj];
            const float po = sm[DBS0 + 192 + jj]  + q[192 + jj];
            const float ig = sigm(pi), gg = tanh_(pg), og = sigm(po);
            sm[DH0 + tid] = og * tanh_(ig * gg);
        }
        __syncthreads();
        if (dsub == 1) {        // cell1: Wih1 . h0
            float a0 = 0.f, a1 = 0.f;
#pragma unroll
            for (int k4 = 0; k4 < 16; ++k4) {
                fma4v(a0, *reinterpret_cast<const float4*>(sm + DH0 + k4 * 4),      wd[k4]);
                fma4v(a1, *reinterpret_cast<const float4*>(sm + DH0 + 64 + k4 * 4), wd[k4]);
            }
            sm[DP1 + g0d] = a0; sm[DP1 + 256 + g0d] = a1;
        }
        __syncthreads();
        if (tid < 128) {        // combine1 + FC (H1 row is wave-local)
            const float* q = sm + DP1 + rr * 256;
            const float pi = sm[DBS1 + jj]        + q[jj];
            const float pg = sm[DBS1 + 128 + jj]  + q[128 + jj];
            const float po = sm[DBS1 + 192 + jj]  + q[192 + jj];
            const float ig = sigm(pi), gg = tanh_(pg), og = sigm(po);
            sm[DH1 + tid] = og * tanh_(ig * gg);
            float acc = bfc_j;
            const float4* hp = reinterpret_cast<const float4*>(sm + DH1 + rr * 64);
#pragma unroll
            for (int k4 = 0; k4 < 16; ++k4) {
                const float4 hv = hp[k4];
                const float* wp = sm + DWFC + k4 * 256;
                acc = fmaf(hv.x, wp[jj],       acc);
                acc = fmaf(hv.y, wp[64 + jj],  acc);
                acc = fmaf(hv.z, wp[128 + jj], acc);
                acc = fmaf(hv.w, wp[192 + jj], acc);
            }
            out[(size_t)(r0 + rr) * PRED * DIM + p * DIM + jj] = acc;
            sm[DDB + tid] = acc;
        }
        __syncthreads();
    }
}

// ===================== FALLBACK: proven 512-thr baseline (1810 us) ==========
#define BP0O   0
#define BP1O   4096
#define BWFCO  8192
#define BH0O   12288
#define BH1O   12544
#define BDBO   12800
#define BBS0O  13056
#define BBS1O  13312
#define BBFCO  13568
#define BSMF   13632
#define BSMEM_BYTES (BSMF * 4)

extern "C" __global__ void __launch_bounds__(512, 2)
rnn_fused_base(const float* __restrict__ x,
          const float* __restrict__ Wih0, const float* __restrict__ Whh0,
          const float* __restrict__ bih0, const float* __restrict__ bhh0,
          const float* __restrict__ Wih1, const float* __restrict__ Whh1,
          const float* __restrict__ bih1, const float* __restrict__ bhh1,
          const float* __restrict__ Wfc,  const float* __restrict__ bfc,
          float* __restrict__ out)
{
    extern __shared__ float sm[];
    const int tid = threadIdx.x;
    const int bid = blockIdx.x;
    const int grp = tid >> 7;
    const int m   = grp & 1;
    const int kh  = grp >> 1;
    const int gp  = tid & 127;
    const int g0  = gp, g1 = gp + 128;
    const int rr  = (tid & 255) >> 6;
    const int jj  = tid & 63;

    if (tid < GATES) {
        sm[BBS0O + tid] = bih0[tid] + bhh0[tid];
        sm[BBS1O + tid] = bih1[tid] + bhh1[tid];
    }
    if (tid < DIM) sm[BBFCO + tid] = bfc[tid];
    if (tid < 256) { sm[BH0O + tid] = 0.0f; sm[BH1O + tid] = 0.0f; }
    for (int idx = tid; idx < DIM * DIM; idx += 512) {
        const int j = idx >> 6, k = idx & 63;
        sm[BWFCO + (k >> 2) * 256 + (k & 3) * 64 + j] = Wfc[idx];
    }

    const float* Wsrc0 = m ? Whh0 : Wih0;
    const float* Wsrc1 = m ? Whh1 : Wih1;
    float4 w0a[8], w0b[8], w1a[8], w1b[8];
#pragma unroll
    for (int k4 = 0; k4 < 8; ++k4) {
        w0a[k4] = *reinterpret_cast<const float4*>(Wsrc0 + g0 * DIM + kh * 32 + k4 * 4);
        w0b[k4] = *reinterpret_cast<const float4*>(Wsrc0 + g1 * DIM + kh * 32 + k4 * 4);
        w1a[k4] = *reinterpret_cast<const float4*>(Wsrc1 + g0 * DIM + kh * 32 + k4 * 4);
        w1b[k4] = *reinterpret_cast<const float4*>(Wsrc1 + g1 * DIM + kh * 32 + k4 * 4);
    }
    __syncthreads();

    const int row0 = bid * 4;
    const float* xr0 = x + (size_t)(row0 + 0) * TSEQ * DIM + kh * 32;
    const float* xr1 = x + (size_t)(row0 + 1) * TSEQ * DIM + kh * 32;
    const float* xr2 = x + (size_t)(row0 + 2) * TSEQ * DIM + kh * 32;
    const float* xr3 = x + (size_t)(row0 + 3) * TSEQ * DIM + kh * 32;

    const int pb = grp * 1024;
    float c_state = 0.0f;

    for (int s = 0; s < TSEQ; ++s) {
        if (s != 0 && tid >= 256) {
            float pi = sm[BBS1O + jj],       pf = sm[BBS1O + 64 + jj];
            float pg = sm[BBS1O + 128 + jj], po = sm[BBS1O + 192 + jj];
#pragma unroll
            for (int cp = 0; cp < 4; ++cp) {
                const float* p = sm + BP1O + cp * 1024 + rr * 256;
                pi += p[jj]; pf += p[64 + jj]; pg += p[128 + jj]; po += p[192 + jj];
            }
            const float ig = sigm(pi), fg = sigm(pf), gg = tanh_(pg), og = sigm(po);
            c_state = fmaf(fg, c_state, ig * gg);
            sm[BH1O + (tid & 255)] = og * tanh_(c_state);
        }
        {
            float acc[8];
#pragma unroll
            for (int i = 0; i < 8; ++i) acc[i] = 0.0f;
            if (m == 0) {
                const int so = s * DIM;
#pragma unroll
                for (int k4 = 0; k4 < 8; ++k4) {
                    const float4 v0 = *reinterpret_cast<const float4*>(xr0 + so + k4 * 4);
                    const float4 v1 = *reinterpret_cast<const float4*>(xr1 + so + k4 * 4);
                    const float4 v2 = *reinterpret_cast<const float4*>(xr2 + so + k4 * 4);
                    const float4 v3 = *reinterpret_cast<const float4*>(xr3 + so + k4 * 4);
                    fma4v(acc[0], v0, w0a[k4]); fma4v(acc[1], v0, w0b[k4]);
                    fma4v(acc[2], v1, w0a[k4]); fma4v(acc[3], v1, w0b[k4]);
                    fma4v(acc[4], v2, w0a[k4]); fma4v(acc[5], v2, w0b[k4]);
                    fma4v(acc[6], v3, w0a[k4]); fma4v(acc[7], v3, w0b[k4]);
                }
            } else {
#pragma unroll
                for (int k4 = 0; k4 < 8; ++k4) {
                    const float4 v0 = *reinterpret_cast<const float4*>(sm + BH0O + 0 * 64 + kh * 32 + k4 * 4);
                    const float4 v1 = *reinterpret_cast<const float4*>(sm + BH0O + 1 * 64 + kh * 32 + k4 * 4);
                    const float4 v2 = *reinterpret_cast<const float4*>(sm + BH0O + 2 * 64 + kh * 32 + k4 * 4);
                    const float4 v3 = *reinterpret_cast<const float4*>(sm + BH0O + 3 * 64 + kh * 32 + k4 * 4);
                    fma4v(acc[0], v0, w0a[k4]); fma4v(acc[1], v0, w0b[k4]);
                    fma4v(acc[2], v1, w0a[k4]); fma4v(acc[3], v1, w0b[k4]);
                    fma4v(acc[4], v2, w0a[k4]); fma4v(acc[5], v2, w0b[k4]);
                    fma4v(acc[6], v3, w0a[k4]); fma4v(acc[7], v3, w0b[k4]);
                }
            }
            sm[BP0O + pb + 0 * 256 + g0] = acc[0]; sm[BP0O + pb + 0 * 256 + g1] = acc[1];
            sm[BP0O + pb + 1 * 256 + g0] = acc[2]; sm[BP0O + pb + 1 * 256 + g1] = acc[3];
            sm[BP0O + pb + 2 * 256 + g0] = acc[4]; sm[BP0O + pb + 2 * 256 + g1] = acc[5];
            sm[BP0O + pb + 3 * 256 + g0] = acc[6]; sm[BP0O + pb + 3 * 256 + g1] = acc[7];
        }
        __syncthreads();

        if (tid < 256) {
            float pi = sm[BBS0O + jj],       pf = sm[BBS0O + 64 + jj];
            float pg = sm[BBS0O + 128 + jj], po = sm[BBS0O + 192 + jj];
#pragma unroll
            for (int cp = 0; cp < 4; ++cp) {
                const float* p = sm + BP0O + cp * 1024 + rr * 256;
                pi += p[jj]; pf += p[64 + jj]; pg += p[128 + jj]; po += p[192 + jj];
            }
            const float ig = sigm(pi), fg = sigm(pf), gg = tanh_(pg), og = sigm(po);
            c_state = fmaf(fg, c_state, ig * gg);
            sm[BH0O + tid] = og * tanh_(c_state);
        }
        __syncthreads();

        {
            const int ib = m ? BH1O : BH0O;
            float acc[8];
#pragma unroll
            for (int i = 0; i < 8; ++i) acc[i] = 0.0f;
#pragma unroll
            for (int k4 = 0; k4 < 8; ++k4) {
                const float4 v0 = *reinterpret_cast<const float4*>(sm + ib + 0 * 64 + kh * 32 + k4 * 4);
                const float4 v1 = *reinterpret_cast<const float4*>(sm + ib + 1 * 64 + kh * 32 + k4 * 4);
                const float4 v2 = *reinterpret_cast<const float4*>(sm + ib + 2 * 64 + kh * 32 + k4 * 4);
                const float4 v3 = *reinterpret_cast<const float4*>(sm + ib + 3 * 64 + kh * 32 + k4 * 4);
                fma4v(acc[0], v0, w1a[k4]); fma4v(acc[1], v0, w1b[k4]);
                fma4v(acc[2], v1, w1a[k4]); fma4v(acc[3], v1, w1b[k4]);
                fma4v(acc[4], v2, w1a[k4]); fma4v(acc[5], v2, w1b[k4]);
                fma4v(acc[6], v3, w1a[k4]); fma4v(acc[7], v3, w1b[k4]);
            }
            sm[BP1O + pb + 0 * 256 + g0] = acc[0]; sm[BP1O + pb + 0 * 256 + g1] = acc[1];
            sm[BP1O + pb + 1 * 256 + g0] = acc[2]; sm[BP1O + pb + 1 * 256 + g1] = acc[3];
            sm[BP1O + pb + 2 * 256 + g0] = acc[4]; sm[BP1O + pb + 2 * 256 + g1] = acc[5];
            sm[BP1O + pb + 3 * 256 + g0] = acc[6]; sm[BP1O + pb + 3 * 256 + g1] = acc[7];
        }
        __syncthreads();
    }

    if (tid >= 256) {
        float pi = sm[BBS1O + jj],       pf = sm[BBS1O + 64 + jj];
        float pg = sm[BBS1O + 128 + jj], po = sm[BBS1O + 192 + jj];
#pragma unroll
        for (int cp = 0; cp < 4; ++cp) {
            const float* p = sm + BP1O + cp * 1024 + rr * 256;
            pi += p[jj]; pf += p[64 + jj]; pg += p[128 + jj]; po += p[192 + jj];
        }
        const float ig = sigm(pi), fg = sigm(pf), gg = tanh_(pg), og = sigm(po);
        c_state = fmaf(fg, c_state, ig * gg);
        sm[BDBO + (tid & 255)] = og * tanh_(c_state);
    }
    __syncthreads();

    const float bfc_j = sm[BBFCO + jj];

    for (int p = 0; p < PRED; ++p) {
        if (m == 0) {
            float acc[8];
#pragma unroll
            for (int i = 0; i < 8; ++i) acc[i] = 0.0f;
#pragma unroll
            for (int k4 = 0; k4 < 8; ++k4) {
                const float4 v0 = *reinterpret_cast<const float4*>(sm + BDBO + 0 * 64 + kh * 32 + k4 * 4);
                const float4 v1 = *reinterpret_cast<const float4*>(sm + BDBO + 1 * 64 + kh * 32 + k4 * 4);
                const float4 v2 = *reinterpret_cast<const float4*>(sm + BDBO + 2 * 64 + kh * 32 + k4 * 4);
                const float4 v3 = *reinterpret_cast<const float4*>(sm + BDBO + 3 * 64 + kh * 32 + k4 * 4);
                fma4v(acc[0], v0, w0a[k4]); fma4v(acc[1], v0, w0b[k4]);
                fma4v(acc[2], v1, w0a[k4]); fma4v(acc[3], v1, w0b[k4]);
                fma4v(acc[4], v2, w0a[k4]); fma4v(acc[5], v2, w0b[k4]);
                fma4v(acc[6], v3, w0a[k4]); fma4v(acc[7], v3, w0b[k4]);
            }
            sm[BP0O + pb + 0 * 256 + g0] = acc[0]; sm[BP0O + pb + 0 * 256 + g1] = acc[1];
            sm[BP0O + pb + 1 * 256 + g0] = acc[2]; sm[BP0O + pb + 1 * 256 + g1] = acc[3];
            sm[BP0O + pb + 2 * 256 + g0] = acc[4]; sm[BP0O + pb + 2 * 256 + g1] = acc[5];
            sm[BP0O + pb + 3 * 256 + g0] = acc[6]; sm[BP0O + pb + 3 * 256 + g1] = acc[7];
        }
        __syncthreads();
        if (tid < 256) {
            float pi = sm[BBS0O + jj], pg = sm[BBS0O + 128 + jj], po = sm[BBS0O + 192 + jj];
            {
                const float* pA = sm + BP0O + 0 * 1024 + rr * 256;
                const float* pB = sm + BP0O + 2 * 1024 + rr * 256;
                pi += pA[jj] + pB[jj];
                pg += pA[128 + jj] + pB[128 + jj];
                po += pA[192 + jj] + pB[192 + jj];
            }
            const float ig = sigm(pi), gg = tanh_(pg), og = sigm(po);
            sm[BH0O + tid] = og * tanh_(ig * gg);
        }
        __syncthreads();

        if (m == 0) {
            float acc[8];
#pragma unroll
            for (int i = 0; i < 8; ++i) acc[i] = 0.0f;
#pragma unroll
            for (int k4 = 0; k4 < 8; ++k4) {
                const float4 v0 = *reinterpret_cast<const float4*>(sm + BH0O + 0 * 64 + kh * 32 + k4 * 4);
                const float4 v1 = *reinterpret_cast<const float4*>(sm + BH0O + 1 * 64 + kh * 32 + k4 * 4);
                const float4 v2 = *reinterpret_cast<const float4*>(sm + BH0O + 2 * 64 + kh * 32 + k4 * 4);
                const float4 v3 = *reinterpret_cast<const float4*>(sm + BH0O + 3 * 64 + kh * 32 + k4 * 4);
                fma4v(acc[0], v0, w1a[k4]); fma4v(acc[1], v0, w1b[k4]);
                fma4v(acc[2], v1, w1a[k4]); fma4v(acc[3], v1, w1b[k4]);
                fma4v(acc[4], v2, w1a[k4]); fma4v(acc[5], v2, w1b[k4]);
                fma4v(acc[6], v3, w1a[k4]); fma4v(acc[7], v3, w1b[k4]);
            }
            sm[BP1O + pb + 0 * 256 + g0] = acc[0]; sm[BP1O + pb + 0 * 256 + g1] = acc[1];
            sm[BP1O + pb + 1 * 256 + g0] = acc[2]; sm[BP1O + pb + 1 * 256 + g1] = acc[3];
            sm[BP1O + pb + 2 * 256 + g0] = acc[4]; sm[BP1O + pb + 2 * 256 + g1] = acc[5];
            sm[BP1O + pb + 3 * 256 + g0] = acc[6]; sm[BP1O + pb + 3 * 256 + g1] = acc[7];
        }
        __syncthreads();
        if (tid >= 256) {
            float pi = sm[BBS1O + jj], pg = sm[BBS1O + 128 + jj], po = sm[BBS1O + 192 + jj];
            {
                const float* pA = sm + BP1O + 0 * 1024 + rr * 256;
                const float* pB = sm + BP1O + 2 * 1024 + rr * 256;
                pi += pA[jj] + pB[jj];
                pg += pA[128 + jj] + pB[128 + jj];
                po += pA[192 + jj] + pB[192 + jj];
            }
            const float ig = sigm(pi), gg = tanh_(pg), og = sigm(po);
            sm[BH1O + (tid & 255)] = og * tanh_(ig * gg);
        }
        __syncthreads();

        if (tid < 256) {
            float acc = bfc_j;
            const float4* hp = reinterpret_cast<const float4*>(sm + BH1O + rr * 64);
#pragma unroll
            for (int k4 = 0; k4 < 16; ++k4) {
                const float4 hv = hp[k4];
                const float* wp = sm + BWFCO + k4 * 256;
                acc = fmaf(hv.x, wp[jj],       acc);
                acc = fmaf(hv.y, wp[64 + jj],  acc);
                acc = fmaf(hv.z, wp[128 + jj], acc);
                acc = fmaf(hv.w, wp[192 + jj], acc);
            }
            out[(size_t)(row0 + rr) * PRED * DIM + p * DIM + jj] = acc;
            sm[BDBO + tid] = acc;
        }
        __syncthreads();
    }
}

extern "C" void kernel_launch(void* const* d_in, const int* in_sizes, int n_in,
                              void* d_out, int out_size, void* d_ws, size_t ws_size,
                              hipStream_t stream) {
    const float* x    = (const float*)d_in[0];
    const float* Wih0 = (const float*)d_in[1];
    const float* Whh0 = (const float*)d_in[2];
    const float* bih0 = (const float*)d_in[3];
    const float* bhh0 = (const float*)d_in[4];
    const float* Wih1 = (const float*)d_in[5];
    const float* Whh1 = (const float*)d_in[6];
    const float* bih1 = (const float*)d_in[7];
    const float* bhh1 = (const float*)d_in[8];
    const float* Wfc  = (const float*)d_in[9];
    const float* bfc  = (const float*)d_in[10];
    float* out = (float*)d_out;

    // ws layout (floats): 4 state vectors (h0,c0,h1,c1: 1024x64 each),
    // h0 sequence (1024x336x64), pre buffer (1024 x tc x 256)
    const size_t base_fl = 4 * (size_t)NB * DIM + (size_t)NB * TSEQ * DIM;
    int tc = 0;
    if (d_ws) {
        const int cands[3] = {336, 168, 112};
        for (int i = 0; i < 3; ++i) {
            const size_t need = (base_fl + (size_t)NB * cands[i] * GATES) * 4;
            if (ws_size >= need) { tc = cands[i]; break; }
        }
    }
    if (tc == 0) {
        hipLaunchKernelGGL(rnn_fused_base, dim3(NB / 4), dim3(512), BSMEM_BYTES, stream,
                           x, Wih0, Whh0, bih0, bhh0, Wih1, Whh1, bih1, bhh1, Wfc, bfc, out);
        return;
    }

    float* wsf   = (float*)d_ws;
    float* st0h  = wsf;
    float* st0c  = wsf + (size_t)NB * DIM;
    float* st1h  = wsf + 2 * (size_t)NB * DIM;
    float* st1c  = wsf + 3 * (size_t)NB * DIM;
    float* h0seq = wsf + 4 * (size_t)NB * DIM;
    float* pre   = wsf + base_fl;

    const int nch = TSEQ / tc;
    for (int i = 0; i < nch; ++i) {
        const int t0 = i * tc;
        hipLaunchKernelGGL(gemm_pre, dim3(NB), dim3(512), 0, stream,
                           x + (size_t)t0 * DIM, Wih0, bih0, bhh0, pre, tc);
        hipLaunchKernelGGL(lstm_recur, dim3(NB / 2), dim3(512), 0, stream,
                           pre, tc, t0, Whh0, h0seq, st0h, st0c, (int)(i == 0));
        hipLaunchKernelGGL(gemm_pre, dim3(NB), dim3(512), 0, stream,
                           h0seq + (size_t)t0 * DIM, Wih1, bih1, bhh1, pre, tc);
        hipLaunchKernelGGL(lstm_recur, dim3(NB / 2), dim3(512), 0, stream,
                           pre, tc, t0, Whh1, (float*)nullptr, st1h, st1c, (int)(i == 0));
    }
    hipLaunchKernelGGL(lstm_dec, dim3(NB / 2), dim3(512), 0, stream,
                       Wih0, Wih1, Wfc, bih0, bhh0, bih1, bhh1, bfc, st1h, out);
}

// Round 10
// 1524.912 us; speedup vs baseline: 1.2035x; 1.2035x over previous
//
#include <hip/hip_runtime.h>

#define NB    1024
#define TSEQ  336
#define DIM   64
#define GATES 256
#define PRED  96

// ========================= MULTI-KERNEL PIPELINE (v3) ========================
// R8 (1427 us) proven: gemm_pre + lstm_recur + dec, one weight matrix per
// resident kernel. R9's shfl-recur regressed 3.5x (longer serial chain:
// dependent shuffles + 4x redundant transcendentals beat the barrier it
// saved) -> reverted verbatim to R8. R10 change: lstm_dec runs 1 batch row
// per block (grid 1024, 4 blocks/CU at ~116 regs) so independent decode
// chains hide each other's barrier latency.

__device__ __forceinline__ float sigm(float v)  { return 1.0f / (1.0f + __expf(-v)); }
__device__ __forceinline__ float tanh_(float v) { return 1.0f - 2.0f / (__expf(2.0f * v) + 1.0f); }

__device__ __forceinline__ void fma4v(float& acc, const float4 xv, const float4 w) {
    acc = fmaf(xv.x, w.x, acc); acc = fmaf(xv.y, w.y, acc);
    acc = fmaf(xv.z, w.z, acc); acc = fmaf(xv.w, w.w, acc);
}

// ---------------- kernel 1: pre = in @ W^T + ba + bb (R8 verbatim) ----------
extern "C" __global__ void __launch_bounds__(512, 4)
gemm_pre(const float* __restrict__ in,   // [1024][TSEQ][64], pre-offset by t0*64
         const float* __restrict__ W,    // [256][64]
         const float* __restrict__ ba, const float* __restrict__ bb,
         float* __restrict__ pre,        // [1024][tcount][256]
         int tcount)
{
    __shared__ __align__(16) float xt[2][512];
    __shared__ __align__(16) float pp[2 * 2048];   // [kh][t8*256+g]
    const int tid = threadIdx.x;
    const int row = blockIdx.x;
    const int g   = tid & 255;
    const int kh  = tid >> 8;

    float4 w[8];
#pragma unroll
    for (int k4 = 0; k4 < 8; ++k4)
        w[k4] = *reinterpret_cast<const float4*>(W + g * DIM + kh * 32 + k4 * 4);
    const float bs = ba[g] + bb[g];

    const float* rin  = in  + (size_t)row * (TSEQ * DIM);
    float*       rout = pre + (size_t)row * tcount * GATES;
    const int ntile = tcount >> 3;

    xt[0][tid] = rin[tid];
    __syncthreads();
    for (int tile = 0; tile < ntile; ++tile) {
        const int cur = tile & 1;
        float pa[8];
#pragma unroll
        for (int t8 = 0; t8 < 8; ++t8) {
            const float* xb = &xt[cur][t8 * 64 + kh * 32];
            float a = 0.f;
#pragma unroll
            for (int k4 = 0; k4 < 8; ++k4)
                fma4v(a, *reinterpret_cast<const float4*>(xb + k4 * 4), w[k4]);
            pa[t8] = a;
        }
#pragma unroll
        for (int t8 = 0; t8 < 8; ++t8)
            pp[kh * 2048 + t8 * 256 + g] = pa[t8];
        if (tile + 1 < ntile)                       // prefetch next x tile
            xt[cur ^ 1][tid] = rin[(tile + 1) * 512 + tid];
        __syncthreads();
        const int tb = tile * 8;
#pragma unroll
        for (int q = 0; q < 4; ++q) {               // combine kh pairs + store
            const int t8 = q * 2 + kh;
            rout[(size_t)(tb + t8) * GATES + g] =
                pp[t8 * 256 + g] + pp[2048 + t8 * 256 + g] + bs;
        }
        __syncthreads();
    }
}

// ---------------- kernel 2: hh-only LSTM recurrence (R8 verbatim) -----------
extern "C" __global__ void __launch_bounds__(512, 4)
lstm_recur(const float* __restrict__ pre, int tcount, int t0,
           const float* __restrict__ Whh,
           float* __restrict__ hseq,               // [1024][TSEQ][64] or null
           float* __restrict__ hstate, float* __restrict__ cstate, // [1024][64]
           int zero_init)
{
    __shared__ __align__(16) float Hs[128];        // h for 2 rows
    __shared__ __align__(16) float Ps[1024];       // partials [kh][row][256]
    const int tid = threadIdx.x;
    const int r0  = blockIdx.x * 2;
    const int g   = tid & 255;
    const int kh  = tid >> 8;
    const int rr  = (tid >> 6) & 1;                // combine lane row (tid<128)
    const int jj  = tid & 63;

    float4 w[8];
#pragma unroll
    for (int k4 = 0; k4 < 8; ++k4)
        w[k4] = *reinterpret_cast<const float4*>(Whh + g * DIM + kh * 32 + k4 * 4);

    const size_t prow = (size_t)tcount * GATES;
    float c = 0.f;
    float pvA0 = 0.f, pvA1 = 0.f, pvA2 = 0.f, pvA3 = 0.f;   // pre[t]
    float pvB0 = 0.f, pvB1 = 0.f, pvB2 = 0.f, pvB3 = 0.f;   // pre[t+1]
    if (tid < 128) {
        if (zero_init) Hs[tid] = 0.f;
        else { Hs[tid] = hstate[(r0 + rr) * DIM + jj]; c = cstate[(r0 + rr) * DIM + jj]; }
        const float* p0 = pre + (size_t)(r0 + rr) * prow + jj;
        pvA0 = p0[0]; pvA1 = p0[64]; pvA2 = p0[128]; pvA3 = p0[192];
        const float* p1 = p0 + GATES;
        pvB0 = p1[0]; pvB1 = p1[64]; pvB2 = p1[128]; pvB3 = p1[192];
    }
    __syncthreads();

    float hlast = 0.f;
    for (int t = 0; t < tcount; ++t) {
        // matvec (all lanes): 2 rows x 32 MAC from uniform LDS broadcasts
        float a0 = 0.f, a1 = 0.f;
        const float* hb0 = Hs + kh * 32;
        const float* hb1 = Hs + 64 + kh * 32;
#pragma unroll
        for (int k4 = 0; k4 < 8; ++k4) {
            fma4v(a0, *reinterpret_cast<const float4*>(hb0 + k4 * 4), w[k4]);
            fma4v(a1, *reinterpret_cast<const float4*>(hb1 + k4 * 4), w[k4]);
        }
        Ps[kh * 512 + g]       = a0;
        Ps[kh * 512 + 256 + g] = a1;
        __syncthreads();

        if (tid < 128) {
            float xi = pvA0, xf = pvA1, xg = pvA2, xo = pvA3;
            pvA0 = pvB0; pvA1 = pvB1; pvA2 = pvB2; pvA3 = pvB3;
            if (t + 2 < tcount) {                   // prefetch pre[t+2]
                const float* pp = pre + (size_t)(r0 + rr) * prow + (size_t)(t + 2) * GATES + jj;
                pvB0 = pp[0]; pvB1 = pp[64]; pvB2 = pp[128]; pvB3 = pp[192];
            }
            const float* q0 = Ps + rr * 256 + jj;           // kh=0 partials
            const float* q1 = Ps + 512 + rr * 256 + jj;     // kh=1 partials
            xi += q0[0]   + q1[0];
            xf += q0[64]  + q1[64];
            xg += q0[128] + q1[128];
            xo += q0[192] + q1[192];
            const float ig = sigm(xi), fg = sigm(xf), gg = tanh_(xg), og = sigm(xo);
            c = fmaf(fg, c, ig * gg);
            const float h = og * tanh_(c);
            hlast = h;
            Hs[tid] = h;
            if (hseq) hseq[(size_t)(r0 + rr) * (TSEQ * DIM) + (size_t)(t0 + t) * DIM + jj] = h;
        }
        __syncthreads();
    }
    if (tid < 128) {
        hstate[(r0 + rr) * DIM + jj] = hlast;
        cstate[(r0 + rr) * DIM + jj] = c;
    }
}

// ---------------- kernel 3: decoder — 1 ROW PER BLOCK (grid 1024) -----------
// R8 dec structure with rr=0; 4 blocks/CU (≈116 regs, 24KB LDS) so
// independent decode chains hide each other's barrier stalls.
#define DWFC 0
#define DP0  4096
#define DP1  4608
#define DH0  5120
#define DH1  5248
#define DDB  5376
#define DBS0 5504
#define DBS1 5760
#define DBFC 6016
#define DSMF 6080

extern "C" __global__ void __launch_bounds__(512, 2)
lstm_dec(const float* __restrict__ Wih0, const float* __restrict__ Wih1,
         const float* __restrict__ Wfc,
         const float* __restrict__ bih0, const float* __restrict__ bhh0,
         const float* __restrict__ bih1, const float* __restrict__ bhh1,
         const float* __restrict__ bfc,
         const float* __restrict__ h1last, float* __restrict__ out)
{
    __shared__ __align__(16) float sm[DSMF];
    const int tid = threadIdx.x;
    const int row = blockIdx.x;
    const int jj  = tid & 63;
    const int dsub = tid >> 8;          // 0: Wih0 team, 1: Wih1 team
    const int g0d  = tid & 255;

    if (tid < 256) {
        sm[DBS0 + tid] = bih0[tid] + bhh0[tid];
        sm[DBS1 + tid] = bih1[tid] + bhh1[tid];
    }
    if (tid < 64) sm[DBFC + tid] = bfc[tid];
    for (int idx = tid; idx < DIM * DIM; idx += 512) {   // W_fc: (k4,c,j)
        const int j = idx >> 6, k = idx & 63;
        sm[DWFC + (k >> 2) * 256 + (k & 3) * 64 + j] = Wfc[idx];
    }
    if (tid < 64) sm[DDB + tid] = h1last[row * DIM + tid];

    const float* Wsrc = dsub ? Wih1 : Wih0;
    float4 wd[16];
#pragma unroll
    for (int k4 = 0; k4 < 16; ++k4)
        wd[k4] = *reinterpret_cast<const float4*>(Wsrc + g0d * DIM + k4 * 4);
    __syncthreads();
    const float bfc_j = sm[DBFC + jj];

    for (int p = 0; p < PRED; ++p) {
        if (dsub == 0) {        // cell0: Wih0 . db
            float a0 = 0.f;
#pragma unroll
            for (int k4 = 0; k4 < 16; ++k4)
                fma4v(a0, *reinterpret_cast<const float4*>(sm + DDB + k4 * 4), wd[k4]);
            sm[DP0 + g0d] = a0;
        }
        __syncthreads();
        if (tid < 64) {         // combine0: c = i*g
            const float* q = sm + DP0;
            const float pi = sm[DBS0 + jj]        + q[jj];
            const float pg = sm[DBS0 + 128 + jj]  + q[128 + jj];
            const float po = sm[DBS0 + 192 + jj]  + q[192 + jj];
            const float ig = sigm(pi), gg = tanh_(pg), og = sigm(po);
            sm[DH0 + tid] = og * tanh_(ig * gg);
        }
        __syncthreads();
        if (dsub == 1) {        // cell1: Wih1 . h0
            float a0 = 0.f;
#pragma unroll
            for (int k4 = 0; k4 < 16; ++k4)
                fma4v(a0, *reinterpret_cast<const float4*>(sm + DH0 + k4 * 4), wd[k4]);
            sm[DP1 + g0d] = a0;
        }
        __syncthreads();
        if (tid < 64) {         // combine1 + FC (single wave: lgkm-ordered)
            const float* q = sm + DP1;
            const float pi = sm[DBS1 + jj]        + q[jj];
            const float pg = sm[DBS1 + 128 + jj]  + q[128 + jj];
            const float po = sm[DBS1 + 192 + jj]  + q[192 + jj];
            const float ig = sigm(pi), gg = tanh_(pg), og = sigm(po);
            sm[DH1 + tid] = og * tanh_(ig * gg);
            float acc = bfc_j;
            const float4* hp = reinterpret_cast<const float4*>(sm + DH1);
#pragma unroll
            for (int k4 = 0; k4 < 16; ++k4) {
                const float4 hv = hp[k4];
                const float* wp = sm + DWFC + k4 * 256;
                acc = fmaf(hv.x, wp[jj],       acc);
                acc = fmaf(hv.y, wp[64 + jj],  acc);
                acc = fmaf(hv.z, wp[128 + jj], acc);
                acc = fmaf(hv.w, wp[192 + jj], acc);
            }
            out[(size_t)row * PRED * DIM + p * DIM + jj] = acc;
            sm[DDB + tid] = acc;
        }
        __syncthreads();
    }
}

// ===================== FALLBACK: proven 512-thr baseline (1810 us) ==========
#define BP0O   0
#define BP1O   4096
#define BWFCO  8192
#define BH0O   12288
#define BH1O   12544
#define BDBO   12800
#define BBS0O  13056
#define BBS1O  13312
#define BBFCO  13568
#define BSMF   13632
#define BSMEM_BYTES (BSMF * 4)

extern "C" __global__ void __launch_bounds__(512, 2)
rnn_fused_base(const float* __restrict__ x,
          const float* __restrict__ Wih0, const float* __restrict__ Whh0,
          const float* __restrict__ bih0, const float* __restrict__ bhh0,
          const float* __restrict__ Wih1, const float* __restrict__ Whh1,
          const float* __restrict__ bih1, const float* __restrict__ bhh1,
          const float* __restrict__ Wfc,  const float* __restrict__ bfc,
          float* __restrict__ out)
{
    extern __shared__ float sm[];
    const int tid = threadIdx.x;
    const int bid = blockIdx.x;
    const int grp = tid >> 7;
    const int m   = grp & 1;
    const int kh  = grp >> 1;
    const int gp  = tid & 127;
    const int g0  = gp, g1 = gp + 128;
    const int rr  = (tid & 255) >> 6;
    const int jj  = tid & 63;

    if (tid < GATES) {
        sm[BBS0O + tid] = bih0[tid] + bhh0[tid];
        sm[BBS1O + tid] = bih1[tid] + bhh1[tid];
    }
    if (tid < DIM) sm[BBFCO + tid] = bfc[tid];
    if (tid < 256) { sm[BH0O + tid] = 0.0f; sm[BH1O + tid] = 0.0f; }
    for (int idx = tid; idx < DIM * DIM; idx += 512) {
        const int j = idx >> 6, k = idx & 63;
        sm[BWFCO + (k >> 2) * 256 + (k & 3) * 64 + j] = Wfc[idx];
    }

    const float* Wsrc0 = m ? Whh0 : Wih0;
    const float* Wsrc1 = m ? Whh1 : Wih1;
    float4 w0a[8], w0b[8], w1a[8], w1b[8];
#pragma unroll
    for (int k4 = 0; k4 < 8; ++k4) {
        w0a[k4] = *reinterpret_cast<const float4*>(Wsrc0 + g0 * DIM + kh * 32 + k4 * 4);
        w0b[k4] = *reinterpret_cast<const float4*>(Wsrc0 + g1 * DIM + kh * 32 + k4 * 4);
        w1a[k4] = *reinterpret_cast<const float4*>(Wsrc1 + g0 * DIM + kh * 32 + k4 * 4);
        w1b[k4] = *reinterpret_cast<const float4*>(Wsrc1 + g1 * DIM + kh * 32 + k4 * 4);
    }
    __syncthreads();

    const int row0 = bid * 4;
    const float* xr0 = x + (size_t)(row0 + 0) * TSEQ * DIM + kh * 32;
    const float* xr1 = x + (size_t)(row0 + 1) * TSEQ * DIM + kh * 32;
    const float* xr2 = x + (size_t)(row0 + 2) * TSEQ * DIM + kh * 32;
    const float* xr3 = x + (size_t)(row0 + 3) * TSEQ * DIM + kh * 32;

    const int pb = grp * 1024;
    float c_state = 0.0f;

    for (int s = 0; s < TSEQ; ++s) {
        if (s != 0 && tid >= 256) {
            float pi = sm[BBS1O + jj],       pf = sm[BBS1O + 64 + jj];
            float pg = sm[BBS1O + 128 + jj], po = sm[BBS1O + 192 + jj];
#pragma unroll
            for (int cp = 0; cp < 4; ++cp) {
                const float* p = sm + BP1O + cp * 1024 + rr * 256;
                pi += p[jj]; pf += p[64 + jj]; pg += p[128 + jj]; po += p[192 + jj];
            }
            const float ig = sigm(pi), fg = sigm(pf), gg = tanh_(pg), og = sigm(po);
            c_state = fmaf(fg, c_state, ig * gg);
            sm[BH1O + (tid & 255)] = og * tanh_(c_state);
        }
        {
            float acc[8];
#pragma unroll
            for (int i = 0; i < 8; ++i) acc[i] = 0.0f;
            if (m == 0) {
                const int so = s * DIM;
#pragma unroll
                for (int k4 = 0; k4 < 8; ++k4) {
                    const float4 v0 = *reinterpret_cast<const float4*>(xr0 + so + k4 * 4);
                    const float4 v1 = *reinterpret_cast<const float4*>(xr1 + so + k4 * 4);
                    const float4 v2 = *reinterpret_cast<const float4*>(xr2 + so + k4 * 4);
                    const float4 v3 = *reinterpret_cast<const float4*>(xr3 + so + k4 * 4);
                    fma4v(acc[0], v0, w0a[k4]); fma4v(acc[1], v0, w0b[k4]);
                    fma4v(acc[2], v1, w0a[k4]); fma4v(acc[3], v1, w0b[k4]);
                    fma4v(acc[4], v2, w0a[k4]); fma4v(acc[5], v2, w0b[k4]);
                    fma4v(acc[6], v3, w0a[k4]); fma4v(acc[7], v3, w0b[k4]);
                }
            } else {
#pragma unroll
                for (int k4 = 0; k4 < 8; ++k4) {
                    const float4 v0 = *reinterpret_cast<const float4*>(sm + BH0O + 0 * 64 + kh * 32 + k4 * 4);
                    const float4 v1 = *reinterpret_cast<const float4*>(sm + BH0O + 1 * 64 + kh * 32 + k4 * 4);
                    const float4 v2 = *reinterpret_cast<const float4*>(sm + BH0O + 2 * 64 + kh * 32 + k4 * 4);
                    const float4 v3 = *reinterpret_cast<const float4*>(sm + BH0O + 3 * 64 + kh * 32 + k4 * 4);
                    fma4v(acc[0], v0, w0a[k4]); fma4v(acc[1], v0, w0b[k4]);
                    fma4v(acc[2], v1, w0a[k4]); fma4v(acc[3], v1, w0b[k4]);
                    fma4v(acc[4], v2, w0a[k4]); fma4v(acc[5], v2, w0b[k4]);
                    fma4v(acc[6], v3, w0a[k4]); fma4v(acc[7], v3, w0b[k4]);
                }
            }
            sm[BP0O + pb + 0 * 256 + g0] = acc[0]; sm[BP0O + pb + 0 * 256 + g1] = acc[1];
            sm[BP0O + pb + 1 * 256 + g0] = acc[2]; sm[BP0O + pb + 1 * 256 + g1] = acc[3];
            sm[BP0O + pb + 2 * 256 + g0] = acc[4]; sm[BP0O + pb + 2 * 256 + g1] = acc[5];
            sm[BP0O + pb + 3 * 256 + g0] = acc[6]; sm[BP0O + pb + 3 * 256 + g1] = acc[7];
        }
        __syncthreads();

        if (tid < 256) {
            float pi = sm[BBS0O + jj],       pf = sm[BBS0O + 64 + jj];
            float pg = sm[BBS0O + 128 + jj], po = sm[BBS0O + 192 + jj];
#pragma unroll
            for (int cp = 0; cp < 4; ++cp) {
                const float* p = sm + BP0O + cp * 1024 + rr * 256;
                pi += p[jj]; pf += p[64 + jj]; pg += p[128 + jj]; po += p[192 + jj];
            }
            const float ig = sigm(pi), fg = sigm(pf), gg = tanh_(pg), og = sigm(po);
            c_state = fmaf(fg, c_state, ig * gg);
            sm[BH0O + tid] = og * tanh_(c_state);
        }
        __syncthreads();

        {
            const int ib = m ? BH1O : BH0O;
            float acc[8];
#pragma unroll
            for (int i = 0; i < 8; ++i) acc[i] = 0.0f;
#pragma unroll
            for (int k4 = 0; k4 < 8; ++k4) {
                const float4 v0 = *reinterpret_cast<const float4*>(sm + ib + 0 * 64 + kh * 32 + k4 * 4);
                const float4 v1 = *reinterpret_cast<const float4*>(sm + ib + 1 * 64 + kh * 32 + k4 * 4);
                const float4 v2 = *reinterpret_cast<const float4*>(sm + ib + 2 * 64 + kh * 32 + k4 * 4);
                const float4 v3 = *reinterpret_cast<const float4*>(sm + ib + 3 * 64 + kh * 32 + k4 * 4);
                fma4v(acc[0], v0, w1a[k4]); fma4v(acc[1], v0, w1b[k4]);
                fma4v(acc[2], v1, w1a[k4]); fma4v(acc[3], v1, w1b[k4]);
                fma4v(acc[4], v2, w1a[k4]); fma4v(acc[5], v2, w1b[k4]);
                fma4v(acc[6], v3, w1a[k4]); fma4v(acc[7], v3, w1b[k4]);
            }
            sm[BP1O + pb + 0 * 256 + g0] = acc[0]; sm[BP1O + pb + 0 * 256 + g1] = acc[1];
            sm[BP1O + pb + 1 * 256 + g0] = acc[2]; sm[BP1O + pb + 1 * 256 + g1] = acc[3];
            sm[BP1O + pb + 2 * 256 + g0] = acc[4]; sm[BP1O + pb + 2 * 256 + g1] = acc[5];
            sm[BP1O + pb + 3 * 256 + g0] = acc[6]; sm[BP1O + pb + 3 * 256 + g1] = acc[7];
        }
        __syncthreads();
    }

    if (tid >= 256) {
        float pi = sm[BBS1O + jj],       pf = sm[BBS1O + 64 + jj];
        float pg = sm[BBS1O + 128 + jj], po = sm[BBS1O + 192 + jj];
#pragma unroll
        for (int cp = 0; cp < 4; ++cp) {
            const float* p = sm + BP1O + cp * 1024 + rr * 256;
            pi += p[jj]; pf += p[64 + jj]; pg += p[128 + jj]; po += p[192 + jj];
        }
        const float ig = sigm(pi), fg = sigm(pf), gg = tanh_(pg), og = sigm(po);
        c_state = fmaf(fg, c_state, ig * gg);
        sm[BDBO + (tid & 255)] = og * tanh_(c_state);
    }
    __syncthreads();

    const float bfc_j = sm[BBFCO + jj];

    for (int p = 0; p < PRED; ++p) {
        if (m == 0) {
            float acc[8];
#pragma unroll
            for (int i = 0; i < 8; ++i) acc[i] = 0.0f;
#pragma unroll
            for (int k4 = 0; k4 < 8; ++k4) {
                const float4 v0 = *reinterpret_cast<const float4*>(sm + BDBO + 0 * 64 + kh * 32 + k4 * 4);
                const float4 v1 = *reinterpret_cast<const float4*>(sm + BDBO + 1 * 64 + kh * 32 + k4 * 4);
                const float4 v2 = *reinterpret_cast<const float4*>(sm + BDBO + 2 * 64 + kh * 32 + k4 * 4);
                const float4 v3 = *reinterpret_cast<const float4*>(sm + BDBO + 3 * 64 + kh * 32 + k4 * 4);
                fma4v(acc[0], v0, w0a[k4]); fma4v(acc[1], v0, w0b[k4]);
                fma4v(acc[2], v1, w0a[k4]); fma4v(acc[3], v1, w0b[k4]);
                fma4v(acc[4], v2, w0a[k4]); fma4v(acc[5], v2, w0b[k4]);
                fma4v(acc[6], v3, w0a[k4]); fma4v(acc[7], v3, w0b[k4]);
            }
            sm[BP0O + pb + 0 * 256 + g0] = acc[0]; sm[BP0O + pb + 0 * 256 + g1] = acc[1];
            sm[BP0O + pb + 1 * 256 + g0] = acc[2]; sm[BP0O + pb + 1 * 256 + g1] = acc[3];
            sm[BP0O + pb + 2 * 256 + g0] = acc[4]; sm[BP0O + pb + 2 * 256 + g1] = acc[5];
            sm[BP0O + pb + 3 * 256 + g0] = acc[6]; sm[BP0O + pb + 3 * 256 + g1] = acc[7];
        }
        __syncthreads();
        if (tid < 256) {
            float pi = sm[BBS0O + jj], pg = sm[BBS0O + 128 + jj], po = sm[BBS0O + 192 + jj];
            {
                const float* pA = sm + BP0O + 0 * 1024 + rr * 256;
                const float* pB = sm + BP0O + 2 * 1024 + rr * 256;
                pi += pA[jj] + pB[jj];
                pg += pA[128 + jj] + pB[128 + jj];
                po += pA[192 + jj] + pB[192 + jj];
            }
            const float ig = sigm(pi), gg = tanh_(pg), og = sigm(po);
            sm[BH0O + tid] = og * tanh_(ig * gg);
        }
        __syncthreads();

        if (m == 0) {
            float acc[8];
#pragma unroll
            for (int i = 0; i < 8; ++i) acc[i] = 0.0f;
#pragma unroll
            for (int k4 = 0; k4 < 8; ++k4) {
                const float4 v0 = *reinterpret_cast<const float4*>(sm + BH0O + 0 * 64 + kh * 32 + k4 * 4);
                const float4 v1 = *reinterpret_cast<const float4*>(sm + BH0O + 1 * 64 + kh * 32 + k4 * 4);
                const float4 v2 = *reinterpret_cast<const float4*>(sm + BH0O + 2 * 64 + kh * 32 + k4 * 4);
                const float4 v3 = *reinterpret_cast<const float4*>(sm + BH0O + 3 * 64 + kh * 32 + k4 * 4);
                fma4v(acc[0], v0, w1a[k4]); fma4v(acc[1], v0, w1b[k4]);
                fma4v(acc[2], v1, w1a[k4]); fma4v(acc[3], v1, w1b[k4]);
                fma4v(acc[4], v2, w1a[k4]); fma4v(acc[5], v2, w1b[k4]);
                fma4v(acc[6], v3, w1a[k4]); fma4v(acc[7], v3, w1b[k4]);
            }
            sm[BP1O + pb + 0 * 256 + g0] = acc[0]; sm[BP1O + pb + 0 * 256 + g1] = acc[1];
            sm[BP1O + pb + 1 * 256 + g0] = acc[2]; sm[BP1O + pb + 1 * 256 + g1] = acc[3];
            sm[BP1O + pb + 2 * 256 + g0] = acc[4]; sm[BP1O + pb + 2 * 256 + g1] = acc[5];
            sm[BP1O + pb + 3 * 256 + g0] = acc[6]; sm[BP1O + pb + 3 * 256 + g1] = acc[7];
        }
        __syncthreads();
        if (tid >= 256) {
            float pi = sm[BBS1O + jj], pg = sm[BBS1O + 128 + jj], po = sm[BBS1O + 192 + jj];
            {
                const float* pA = sm + BP1O + 0 * 1024 + rr * 256;
                const float* pB = sm + BP1O + 2 * 1024 + rr * 256;
                pi += pA[jj] + pB[jj];
                pg += pA[128 + jj] + pB[128 + jj];
                po += pA[192 + jj] + pB[192 + jj];
            }
            const float ig = sigm(pi), gg = tanh_(pg), og = sigm(po);
            sm[BH1O + (tid & 255)] = og * tanh_(ig * gg);
        }
        __syncthreads();

        if (tid < 256) {
            float acc = bfc_j;
            const float4* hp = reinterpret_cast<const float4*>(sm + BH1O + rr * 64);
#pragma unroll
            for (int k4 = 0; k4 < 16; ++k4) {
                const float4 hv = hp[k4];
                const float* wp = sm + BWFCO + k4 * 256;
                acc = fmaf(hv.x, wp[jj],       acc);
                acc = fmaf(hv.y, wp[64 + jj],  acc);
                acc = fmaf(hv.z, wp[128 + jj], acc);
                acc = fmaf(hv.w, wp[192 + jj], acc);
            }
            out[(size_t)(row0 + rr) * PRED * DIM + p * DIM + jj] = acc;
            sm[BDBO + tid] = acc;
        }
        __syncthreads();
    }
}

extern "C" void kernel_launch(void* const* d_in, const int* in_sizes, int n_in,
                              void* d_out, int out_size, void* d_ws, size_t ws_size,
                              hipStream_t stream) {
    const float* x    = (const float*)d_in[0];
    const float* Wih0 = (const float*)d_in[1];
    const float* Whh0 = (const float*)d_in[2];
    const float* bih0 = (const float*)d_in[3];
    const float* bhh0 = (const float*)d_in[4];
    const float* Wih1 = (const float*)d_in[5];
    const float* Whh1 = (const float*)d_in[6];
    const float* bih1 = (const float*)d_in[7];
    const float* bhh1 = (const float*)d_in[8];
    const float* Wfc  = (const float*)d_in[9];
    const float* bfc  = (const float*)d_in[10];
    float* out = (float*)d_out;

    // ws layout (floats): 4 state vectors (h0,c0,h1,c1: 1024x64 each),
    // h0 sequence (1024x336x64), pre buffer (1024 x tc x 256)
    const size_t base_fl = 4 * (size_t)NB * DIM + (size_t)NB * TSEQ * DIM;
    int tc = 0;
    if (d_ws) {
        const int cands[3] = {336, 168, 112};
        for (int i = 0; i < 3; ++i) {
            const size_t need = (base_fl + (size_t)NB * cands[i] * GATES) * 4;
            if (ws_size >= need) { tc = cands[i]; break; }
        }
    }
    if (tc == 0) {
        hipLaunchKernelGGL(rnn_fused_base, dim3(NB / 4), dim3(512), BSMEM_BYTES, stream,
                           x, Wih0, Whh0, bih0, bhh0, Wih1, Whh1, bih1, bhh1, Wfc, bfc, out);
        return;
    }

    float* wsf   = (float*)d_ws;
    float* st0h  = wsf;
    float* st0c  = wsf + (size_t)NB * DIM;
    float* st1h  = wsf + 2 * (size_t)NB * DIM;
    float* st1c  = wsf + 3 * (size_t)NB * DIM;
    float* h0seq = wsf + 4 * (size_t)NB * DIM;
    float* pre   = wsf + base_fl;

    const int nch = TSEQ / tc;
    for (int i = 0; i < nch; ++i) {
        const int t0 = i * tc;
        hipLaunchKernelGGL(gemm_pre, dim3(NB), dim3(512), 0, stream,
                           x + (size_t)t0 * DIM, Wih0, bih0, bhh0, pre, tc);
        hipLaunchKernelGGL(lstm_recur, dim3(NB / 2), dim3(512), 0, stream,
                           pre, tc, t0, Whh0, h0seq, st0h, st0c, (int)(i == 0));
        hipLaunchKernelGGL(gemm_pre, dim3(NB), dim3(512), 0, stream,
                           h0seq + (size_t)t0 * DIM, Wih1, bih1, bhh1, pre, tc);
        hipLaunchKernelGGL(lstm_recur, dim3(NB / 2), dim3(512), 0, stream,
                           pre, tc, t0, Whh1, (float*)nullptr, st1h, st1c, (int)(i == 0));
    }
    hipLaunchKernelGGL(lstm_dec, dim3(NB), dim3(512), 0, stream,
                       Wih0, Wih1, Wfc, bih0, bhh0, bih1, bhh1, bfc, st1h, out);
}